// Round 11
// baseline (109.568 us; speedup 1.0000x reference)
//
#include <hip/hip_runtime.h>
#include <hip/hip_bf16.h>

#define BATCH 4
#define SEQ   4096
#define DIN   768
#define DOUT  64

typedef __attribute__((ext_vector_type(4))) float f32x4;
typedef __attribute__((ext_vector_type(8))) short short8;
typedef __attribute__((ext_vector_type(4))) short short4v;

#define QSCALE 0.18033688011112043f  /* 0.125 * log2(e) */

static __device__ __forceinline__ unsigned short f2bf(float f) {
    union { float f; unsigned u; } un; un.f = f;
    unsigned r = un.u + 0x7FFF + ((un.u >> 16) & 1);
    return (unsigned short)(r >> 16);
}
static __device__ __forceinline__ float bf2f(unsigned short h) {
    union { unsigned u; float f; } un; un.u = ((unsigned)h) << 16;
    return un.f;
}

// ---------------------------------------------------------------------------
// Kernel 0 (v2, unchanged): weights -> B-fragment order.
// ---------------------------------------------------------------------------
__global__ void wprep_kernel(const float* __restrict__ wq,
                             const float* __restrict__ wk,
                             const float* __restrict__ wv,
                             unsigned short* __restrict__ wF) {
    __shared__ float lds[64][65];
    int o = blockIdx.x / 12, kt = blockIdx.x % 12;
    const float* w = (o == 0) ? wq : (o == 1) ? wk : wv;
    int tid = threadIdx.x;
    int k0 = kt * 64;
    #pragma unroll
    for (int i = 0; i < 16; ++i) {
        int flat = tid + i * 256;
        int kl = flat >> 6, n = flat & 63;
        lds[kl][n] = w[(k0 + kl) * 64 + n];
    }
    __syncthreads();
    int lane = tid & 63;
    int m = lane & 15, g = lane >> 4;
    #pragma unroll
    for (int i = 0; i < 2; ++i) {
        int f = i * 4 + (tid >> 6);
        int t = f >> 1, kcl = f & 1;
        int kc = kt * 2 + kcl;
        int nc = o * 4 + t;
        short8 v;
        #pragma unroll
        for (int j = 0; j < 8; ++j)
            v[j] = (short)f2bf(lds[kcl * 32 + g * 8 + j][t * 16 + m]);
        *(short8*)&wF[(size_t)(nc * 24 + kc) * 512 + lane * 8] = v;
    }
}

// ---------------------------------------------------------------------------
// Kernel 1 (v7, unchanged): QKV projection, fragment-order I/O.
// ---------------------------------------------------------------------------
__global__ void __launch_bounds__(256) proj_kernel(
        const float* __restrict__ x,
        const float* __restrict__ bq,
        const float* __restrict__ bk,
        const float* __restrict__ bv,
        const unsigned short* __restrict__ wF,
        unsigned short* __restrict__ Qf,
        unsigned short* __restrict__ Kf,
        unsigned short* __restrict__ Vf) {
    __shared__ __align__(16) unsigned short xs[16][776];
    __shared__ unsigned short tr[4][16][24];

    int tid = threadIdx.x;
    int w = tid >> 6;
    int lane = tid & 63;
    int m = lane & 15, g = lane >> 4;
    int r0 = blockIdx.x * 16;

    {
        const float* xbase = x + (size_t)r0 * DIN;
        #pragma unroll
        for (int i = 0; i < 12; ++i) {
            int flat4 = tid + i * 256;
            int row = flat4 / 192;
            int c4 = flat4 - row * 192;
            float4 v = *(const float4*)(xbase + (size_t)row * DIN + c4 * 4);
            short4v sv;
            sv[0] = (short)f2bf(v.x); sv[1] = (short)f2bf(v.y);
            sv[2] = (short)f2bf(v.z); sv[3] = (short)f2bf(v.w);
            *(short4v*)&xs[row][c4 * 4] = sv;
        }
    }
    __syncthreads();

    f32x4 acc[3];
    #pragma unroll
    for (int t = 0; t < 3; ++t) acc[t] = (f32x4){0.f, 0.f, 0.f, 0.f};

    for (int kc = 0; kc < 24; ++kc) {
        short8 af = *(const short8*)&xs[m][kc * 32 + g * 8];
        #pragma unroll
        for (int tt = 0; tt < 3; ++tt) {
            int nc = w * 3 + tt;
            short8 bfrg = *(const short8*)(wF + (size_t)(nc * 24 + kc) * 512 + lane * 8);
            acc[tt] = __builtin_amdgcn_mfma_f32_16x16x32_bf16(af, bfrg, acc[tt], 0, 0, 0);
        }
    }

    int b2 = r0 >> 12;
    int ss = r0 & 4095;
    int s = ss >> 5, half = (ss >> 4) & 1;
    #pragma unroll
    for (int tt = 0; tt < 3; ++tt) {
        int nc = w * 3 + tt;
        int o = nc >> 2;
        int t = nc & 3;
        const float* bias_p = (o == 0) ? bq : (o == 1) ? bk : bv;
        float bias = bias_p[t * 16 + m];
        #pragma unroll
        for (int r = 0; r < 4; ++r) {
            float val = acc[tt][r] + bias;
            if (o == 0) val *= QSCALE;
            tr[w][g * 4 + r][m] = f2bf(val);
        }
        if (o < 2) {
            if (g < 2) {
                short8 v8;
                #pragma unroll
                for (int j = 0; j < 8; ++j) v8[j] = (short)tr[w][m][g * 8 + j];
                unsigned short* dst = (o == 0) ? Qf : Kf;
                int c = t >> 1;
                *(short8*)&dst[(size_t)(blockIdx.x * 2 + c) * 512
                               + (((t & 1) * 2 + g) * 16 + m) * 8] = v8;
            }
        } else {
            if (g < 2) {
                short8 v8;
                #pragma unroll
                for (int j = 0; j < 8; ++j) v8[j] = (short)tr[w][g * 8 + j][m];
                *(short8*)&Vf[((size_t)(b2 * 128 + s) * 4 + t) * 512
                              + ((half * 2 + g) * 16 + m) * 8] = v8;
            }
        }
    }
}

// ---------------------------------------------------------------------------
// Kernel 2 (v6): causal flash attention.
// New this round: (1) row-tile-fused schedule — QK(both rt) -> softmax(both)
// -> all 32 P rows written -> ONE LDS wait -> PV(both): rt0's LDS latency
// hides under rt1's softmax; (2) 1-step K/V register prefetch (issue s+8
// loads before computing s) — L2 latency hides under compute.
// ---------------------------------------------------------------------------
__global__ void __launch_bounds__(512, 4) attn_kernel(
        const unsigned short* __restrict__ Qf,
        const unsigned short* __restrict__ Kf,
        const unsigned short* __restrict__ Vf,
        float* __restrict__ out) {
    __shared__ __align__(16) unsigned short P_lds[8][32][36];
    __shared__ __align__(16) unsigned short pacc[8][16][68];
    __shared__ float pm[8][16];
    __shared__ float pl[8][16];

    int j = blockIdx.x;
    int b = (j & 7) >> 1;
    int pair = 127 - ((j >> 3) * 2 + (j & 1));
    int q0 = pair * 32;
    int nsteps = pair + 1;
    int tid = threadIdx.x;
    int w = tid >> 6;
    int lane = tid & 63;
    int m = lane & 15, g = lane >> 4;

    const unsigned short* Qbase = Qf + (size_t)(b * 256 + pair * 2) * 1024 + lane * 8;
    short8 qf[2][2];
    qf[0][0] = *(const short8*)(Qbase);
    qf[0][1] = *(const short8*)(Qbase + 512);
    qf[1][0] = *(const short8*)(Qbase + 1024);
    qf[1][1] = *(const short8*)(Qbase + 1536);

    short8 onesB = (short8){0,0,0,0,0,0,0,0};
    if (m == 0) {
        #pragma unroll
        for (int jj = 0; jj < 8; ++jj) onesB[jj] = (short)0x3F80;
    }

    f32x4 acc[2][5];
    #pragma unroll
    for (int rt = 0; rt < 2; ++rt)
        #pragma unroll
        for (int t = 0; t < 5; ++t) acc[rt][t] = (f32x4){0.f, 0.f, 0.f, 0.f};
    float mrun[2][4];
    #pragma unroll
    for (int rt = 0; rt < 2; ++rt)
        #pragma unroll
        for (int r = 0; r < 4; ++r) mrun[rt][r] = -INFINITY;

    const unsigned short* Kbase = Kf + (size_t)(b * 256) * 1024 + lane * 8;
    const unsigned short* Vbase = Vf + (size_t)(b * 128) * 2048 + lane * 8;

    // preload first step
    short8 kf[4], vf[4];
    if (w < nsteps) {
        #pragma unroll
        for (int t = 0; t < 4; ++t) {
            kf[t] = *(const short8*)(Kbase + (size_t)w * 2048 + t * 512);
            vf[t] = *(const short8*)(Vbase + (size_t)w * 2048 + t * 512);
        }
    }

    for (int s = w; s < nsteps; s += 8) {
        int kv0 = s * 32;
        bool last = (s == nsteps - 1);
        int sn = s + 8;
        // prefetch next step K/V (hides L2 latency under this step's compute)
        short8 kn[4], vn[4];
        if (sn < nsteps) {
            #pragma unroll
            for (int t = 0; t < 4; ++t) {
                kn[t] = *(const short8*)(Kbase + (size_t)sn * 2048 + t * 512);
                vn[t] = *(const short8*)(Vbase + (size_t)sn * 2048 + t * 512);
            }
        }

        // QK^T for BOTH row-tiles
        f32x4 sc[2][2];
        #pragma unroll
        for (int rt = 0; rt < 2; ++rt) {
            sc[rt][0] = (f32x4){0.f, 0.f, 0.f, 0.f};
            sc[rt][1] = (f32x4){0.f, 0.f, 0.f, 0.f};
            sc[rt][0] = __builtin_amdgcn_mfma_f32_16x16x32_bf16(qf[rt][0], kf[0], sc[rt][0], 0, 0, 0);
            sc[rt][0] = __builtin_amdgcn_mfma_f32_16x16x32_bf16(qf[rt][1], kf[1], sc[rt][0], 0, 0, 0);
            sc[rt][1] = __builtin_amdgcn_mfma_f32_16x16x32_bf16(qf[rt][0], kf[2], sc[rt][1], 0, 0, 0);
            sc[rt][1] = __builtin_amdgcn_mfma_f32_16x16x32_bf16(qf[rt][1], kf[3], sc[rt][1], 0, 0, 0);
        }
        if (last) {
            #pragma unroll
            for (int rt = 0; rt < 2; ++rt)
                #pragma unroll
                for (int tt = 0; tt < 2; ++tt)
                    #pragma unroll
                    for (int r = 0; r < 4; ++r)
                        if (kv0 + tt * 16 + m > q0 + rt * 16 + g * 4 + r)
                            sc[rt][tt][r] = -INFINITY;
        }

        // softmax (defer-max) + P writes for BOTH row-tiles
        #pragma unroll
        for (int rt = 0; rt < 2; ++rt) {
            bool need = false;
            #pragma unroll
            for (int r = 0; r < 4; ++r) {
                float th = mrun[rt][r] + 8.0f;
                need = need | (sc[rt][0][r] > th) | (sc[rt][1][r] > th);
            }
            if (__any(need)) {
                float rmax[4];
                #pragma unroll
                for (int r = 0; r < 4; ++r) rmax[r] = fmaxf(sc[rt][0][r], sc[rt][1][r]);
                #pragma unroll
                for (int msk = 1; msk <= 8; msk <<= 1)
                    #pragma unroll
                    for (int r = 0; r < 4; ++r)
                        rmax[r] = fmaxf(rmax[r], __shfl_xor(rmax[r], msk));
                #pragma unroll
                for (int r = 0; r < 4; ++r) {
                    float mnew = fmaxf(mrun[rt][r], rmax[r]);
                    float alpha = __builtin_amdgcn_exp2f(mrun[rt][r] - mnew);
                    mrun[rt][r] = mnew;
                    #pragma unroll
                    for (int t = 0; t < 5; ++t) acc[rt][t][r] *= alpha;
                }
            }
            #pragma unroll
            for (int tt = 0; tt < 2; ++tt)
                #pragma unroll
                for (int r = 0; r < 4; ++r)
                    P_lds[w][rt * 16 + g * 4 + r][tt * 16 + m] =
                        f2bf(__builtin_amdgcn_exp2f(sc[rt][tt][r] - mrun[rt][r]));
        }

        // single LDS wait, then PV for BOTH row-tiles
        short8 pa0 = *(const short8*)&P_lds[w][m][g * 8];
        short8 pa1 = *(const short8*)&P_lds[w][16 + m][g * 8];
        #pragma unroll
        for (int t = 0; t < 4; ++t) {
            acc[0][t] = __builtin_amdgcn_mfma_f32_16x16x32_bf16(pa0, vf[t], acc[0][t], 0, 0, 0);
            acc[1][t] = __builtin_amdgcn_mfma_f32_16x16x32_bf16(pa1, vf[t], acc[1][t], 0, 0, 0);
        }
        acc[0][4] = __builtin_amdgcn_mfma_f32_16x16x32_bf16(pa0, onesB, acc[0][4], 0, 0, 0);
        acc[1][4] = __builtin_amdgcn_mfma_f32_16x16x32_bf16(pa1, onesB, acc[1][4], 0, 0, 0);

        if (sn < nsteps) {
            #pragma unroll
            for (int t = 0; t < 4; ++t) { kf[t] = kn[t]; vf[t] = vn[t]; }
        }
    }

    #pragma unroll
    for (int rt = 0; rt < 2; ++rt) {
        if (m == 0) {
            #pragma unroll
            for (int r = 0; r < 4; ++r) {
                pm[w][g * 4 + r] = mrun[rt][r];
                pl[w][g * 4 + r] = acc[rt][4][r];
            }
        }
        #pragma unroll
        for (int t = 0; t < 4; ++t)
            #pragma unroll
            for (int r = 0; r < 4; ++r)
                pacc[w][g * 4 + r][t * 16 + m] = f2bf(acc[rt][t][r]);
        __syncthreads();

        if (tid < 256) {
            int row = tid >> 4;
            int c4 = (tid & 15) * 4;
            float mmax = pm[0][row];
            #pragma unroll
            for (int w2 = 1; w2 < 8; ++w2) mmax = fmaxf(mmax, pm[w2][row]);
            float lt = 0.f;
            float o0 = 0.f, o1 = 0.f, o2 = 0.f, o3 = 0.f;
            #pragma unroll
            for (int w2 = 0; w2 < 8; ++w2) {
                float sc2 = __builtin_amdgcn_exp2f(pm[w2][row] - mmax);
                lt += pl[w2][row] * sc2;
                short4v pa4 = *(const short4v*)&pacc[w2][row][c4];
                o0 += bf2f((unsigned short)pa4[0]) * sc2;
                o1 += bf2f((unsigned short)pa4[1]) * sc2;
                o2 += bf2f((unsigned short)pa4[2]) * sc2;
                o3 += bf2f((unsigned short)pa4[3]) * sc2;
            }
            float invl = 1.0f / lt;
            float4 res = make_float4(o0 * invl, o1 * invl, o2 * invl, o3 * invl);
            *(float4*)&out[(size_t)(b * SEQ + q0 + rt * 16 + row) * DOUT + c4] = res;
        }
        __syncthreads();
    }
}

// ---------------------------------------------------------------------------
extern "C" void kernel_launch(void* const* d_in, const int* in_sizes, int n_in,
                              void* d_out, int out_size, void* d_ws, size_t ws_size,
                              hipStream_t stream) {
    const float* x  = (const float*)d_in[0];
    const float* wq = (const float*)d_in[1];
    const float* bq = (const float*)d_in[2];
    const float* wk = (const float*)d_in[3];
    const float* bk = (const float*)d_in[4];
    const float* wv = (const float*)d_in[5];
    const float* bv = (const float*)d_in[6];
    float* out = (float*)d_out;

    char* ws = (char*)d_ws;
    unsigned short* wF = (unsigned short*)ws;                       // 294912 B
    unsigned short* Qf = (unsigned short*)(ws + 294912);            // 2 MB
    unsigned short* Kf = (unsigned short*)(ws + 294912 + 2097152);  // 2 MB
    unsigned short* Vf = (unsigned short*)(ws + 294912 + 4194304);  // 2 MB

    wprep_kernel<<<36, 256, 0, stream>>>(wq, wk, wv, wF);
    proj_kernel<<<1024, 256, 0, stream>>>(x, bq, bk, bv, wF, Qf, Kf, Vf);
    attn_kernel<<<512, 512, 0, stream>>>(Qf, Kf, Vf, out);
}

// Round 12
// 53.262 us; speedup vs baseline: 2.0571x; 2.0571x over previous
//
#include <hip/hip_runtime.h>
#include <hip/hip_bf16.h>

#define BATCH 4
#define SEQ   4096
#define DIN   768
#define DOUT  64

typedef __attribute__((ext_vector_type(4))) float f32x4;
typedef __attribute__((ext_vector_type(8))) short short8;
typedef __attribute__((ext_vector_type(4))) short short4v;

#define QSCALE 0.18033688011112043f  /* 0.125 * log2(e) */

static __device__ __forceinline__ unsigned short f2bf(float f) {
    union { float f; unsigned u; } un; un.f = f;
    unsigned r = un.u + 0x7FFF + ((un.u >> 16) & 1);
    return (unsigned short)(r >> 16);
}
static __device__ __forceinline__ float bf2f(unsigned short h) {
    union { unsigned u; float f; } un; un.u = ((unsigned)h) << 16;
    return un.f;
}

// ---------------------------------------------------------------------------
// Kernel 0 (v2, unchanged): weights -> B-fragment order.
// wF[(nc*24+kc)*512 + lane*8 + j] = w_o[kc*32 + g*8 + j][t*16 + m]
// ---------------------------------------------------------------------------
__global__ void wprep_kernel(const float* __restrict__ wq,
                             const float* __restrict__ wk,
                             const float* __restrict__ wv,
                             unsigned short* __restrict__ wF) {
    __shared__ float lds[64][65];
    int o = blockIdx.x / 12, kt = blockIdx.x % 12;
    const float* w = (o == 0) ? wq : (o == 1) ? wk : wv;
    int tid = threadIdx.x;
    int k0 = kt * 64;
    #pragma unroll
    for (int i = 0; i < 16; ++i) {
        int flat = tid + i * 256;
        int kl = flat >> 6, n = flat & 63;
        lds[kl][n] = w[(k0 + kl) * 64 + n];
    }
    __syncthreads();
    int lane = tid & 63;
    int m = lane & 15, g = lane >> 4;
    #pragma unroll
    for (int i = 0; i < 2; ++i) {
        int f = i * 4 + (tid >> 6);
        int t = f >> 1, kcl = f & 1;
        int kc = kt * 2 + kcl;
        int nc = o * 4 + t;
        short8 v;
        #pragma unroll
        for (int j = 0; j < 8; ++j)
            v[j] = (short)f2bf(lds[kcl * 32 + g * 8 + j][t * 16 + m]);
        *(short8*)&wF[(size_t)(nc * 24 + kc) * 512 + lane * 8] = v;
    }
}

// ---------------------------------------------------------------------------
// Kernel 1 (v8): QKV projection, fragment-order I/O, 32 rows/block.
// 512 blocks x 256 thr (4 waves). Halves aggregate wF L2 traffic vs v7
// (each block reads 288KB of wF regardless of row count) and doubles MFMA
// per wF load: per k-chunk each wave does 2 A-frags x 3 B-frags = 6 MFMA.
// ---------------------------------------------------------------------------
__global__ void __launch_bounds__(256) proj_kernel(
        const float* __restrict__ x,
        const float* __restrict__ bq,
        const float* __restrict__ bk,
        const float* __restrict__ bv,
        const unsigned short* __restrict__ wF,
        unsigned short* __restrict__ Qf,
        unsigned short* __restrict__ Kf,
        unsigned short* __restrict__ Vf) {
    __shared__ __align__(16) unsigned short xs[32][776];   // 48.5 KB
    __shared__ unsigned short tr[4][16][24];               // 3 KB

    int tid = threadIdx.x;
    int w = tid >> 6;
    int lane = tid & 63;
    int m = lane & 15, g = lane >> 4;
    int r0 = blockIdx.x * 32;

    // stage x[r0:r0+32][0:768] -> bf16 LDS (coalesced float4)
    {
        const float* xbase = x + (size_t)r0 * DIN;
        #pragma unroll
        for (int i = 0; i < 24; ++i) {
            int flat4 = tid + i * 256;
            int row = flat4 / 192;
            int c4 = flat4 - row * 192;
            float4 v = *(const float4*)(xbase + (size_t)row * DIN + c4 * 4);
            short4v sv;
            sv[0] = (short)f2bf(v.x); sv[1] = (short)f2bf(v.y);
            sv[2] = (short)f2bf(v.z); sv[3] = (short)f2bf(v.w);
            *(short4v*)&xs[row][c4 * 4] = sv;
        }
    }
    __syncthreads();

    f32x4 acc[2][3];
    #pragma unroll
    for (int st = 0; st < 2; ++st)
        #pragma unroll
        for (int t = 0; t < 3; ++t) acc[st][t] = (f32x4){0.f, 0.f, 0.f, 0.f};

    for (int kc = 0; kc < 24; ++kc) {
        short8 af0 = *(const short8*)&xs[m][kc * 32 + g * 8];
        short8 af1 = *(const short8*)&xs[16 + m][kc * 32 + g * 8];
        #pragma unroll
        for (int tt = 0; tt < 3; ++tt) {
            int nc = w * 3 + tt;
            short8 bfrg = *(const short8*)(wF + (size_t)(nc * 24 + kc) * 512 + lane * 8);
            acc[0][tt] = __builtin_amdgcn_mfma_f32_16x16x32_bf16(af0, bfrg, acc[0][tt], 0, 0, 0);
            acc[1][tt] = __builtin_amdgcn_mfma_f32_16x16x32_bf16(af1, bfrg, acc[1][tt], 0, 0, 0);
        }
    }

    // epilogue per 16-row half: bias, LDS transpose, fragment-order stores
    int b2 = r0 >> 12;
    int s = (r0 & 4095) >> 5;          // 32-row block == one 32-kv V step-tile
    #pragma unroll
    for (int st = 0; st < 2; ++st) {
        #pragma unroll
        for (int tt = 0; tt < 3; ++tt) {
            int nc = w * 3 + tt;
            int o = nc >> 2;
            int t = nc & 3;
            const float* bias_p = (o == 0) ? bq : (o == 1) ? bk : bv;
            float bias = bias_p[t * 16 + m];
            #pragma unroll
            for (int r = 0; r < 4; ++r) {
                float val = acc[st][tt][r] + bias;
                if (o == 0) val *= QSCALE;
                tr[w][g * 4 + r][m] = f2bf(val);
            }
            if (o < 2) {
                if (g < 2) {
                    short8 v8;
                    #pragma unroll
                    for (int j = 0; j < 8; ++j) v8[j] = (short)tr[w][m][g * 8 + j];
                    unsigned short* dst = (o == 0) ? Qf : Kf;
                    int c = t >> 1;
                    *(short8*)&dst[(size_t)((blockIdx.x * 2 + st) * 2 + c) * 512
                                   + (((t & 1) * 2 + g) * 16 + m) * 8] = v8;
                }
            } else {
                if (g < 2) {
                    short8 v8;
                    #pragma unroll
                    for (int j = 0; j < 8; ++j) v8[j] = (short)tr[w][g * 8 + j][m];
                    *(short8*)&Vf[((size_t)(b2 * 128 + s) * 4 + t) * 512
                                  + ((st * 2 + g) * 16 + m) * 8] = v8;
                }
            }
        }
    }
}

// ---------------------------------------------------------------------------
// Kernel 2 (v5, reverted to round-10 exactly): causal flash attention.
// Fragment-order contiguous loads; 512 blocks x 512 thr; 32 q-rows/block;
// 8-way KV split; defer-max; ones-column row-sum; LDS combine.
// (Round-11's fused+prefetch variant spilled ~100 dw/thread -> reverted.)
// ---------------------------------------------------------------------------
__global__ void __launch_bounds__(512, 4) attn_kernel(
        const unsigned short* __restrict__ Qf,
        const unsigned short* __restrict__ Kf,
        const unsigned short* __restrict__ Vf,
        float* __restrict__ out) {
    __shared__ __align__(16) unsigned short P_lds[8][32][36];
    __shared__ __align__(16) unsigned short pacc[8][16][68];
    __shared__ float pm[8][16];
    __shared__ float pl[8][16];

    int j = blockIdx.x;
    int b = (j & 7) >> 1;
    int pair = 127 - ((j >> 3) * 2 + (j & 1));
    int q0 = pair * 32;
    int nsteps = pair + 1;
    int tid = threadIdx.x;
    int w = tid >> 6;
    int lane = tid & 63;
    int m = lane & 15, g = lane >> 4;

    const unsigned short* Qbase = Qf + (size_t)(b * 256 + pair * 2) * 1024 + lane * 8;
    short8 qf[2][2];
    qf[0][0] = *(const short8*)(Qbase);
    qf[0][1] = *(const short8*)(Qbase + 512);
    qf[1][0] = *(const short8*)(Qbase + 1024);
    qf[1][1] = *(const short8*)(Qbase + 1536);

    short8 onesB = (short8){0,0,0,0,0,0,0,0};
    if (m == 0) {
        #pragma unroll
        for (int jj = 0; jj < 8; ++jj) onesB[jj] = (short)0x3F80;
    }

    f32x4 acc[2][5];
    #pragma unroll
    for (int rt = 0; rt < 2; ++rt)
        #pragma unroll
        for (int t = 0; t < 5; ++t) acc[rt][t] = (f32x4){0.f, 0.f, 0.f, 0.f};
    float mrun[2][4];
    #pragma unroll
    for (int rt = 0; rt < 2; ++rt)
        #pragma unroll
        for (int r = 0; r < 4; ++r) mrun[rt][r] = -INFINITY;

    const unsigned short* Kbase = Kf + (size_t)(b * 256) * 1024 + lane * 8;
    const unsigned short* Vbase = Vf + (size_t)(b * 128) * 2048 + lane * 8;

    for (int s = w; s < nsteps; s += 8) {
        int kv0 = s * 32;
        short8 kf[4];
        kf[0] = *(const short8*)(Kbase + (size_t)s * 2048);
        kf[1] = *(const short8*)(Kbase + (size_t)s * 2048 + 512);
        kf[2] = *(const short8*)(Kbase + (size_t)s * 2048 + 1024);
        kf[3] = *(const short8*)(Kbase + (size_t)s * 2048 + 1536);
        short8 vcur[4];
        #pragma unroll
        for (int t = 0; t < 4; ++t)
            vcur[t] = *(const short8*)(Vbase + (size_t)s * 2048 + t * 512);
        bool last = (s == nsteps - 1);

        #pragma unroll
        for (int rt = 0; rt < 2; ++rt) {
            f32x4 sc[2];
            sc[0] = (f32x4){0.f, 0.f, 0.f, 0.f};
            sc[1] = (f32x4){0.f, 0.f, 0.f, 0.f};
            sc[0] = __builtin_amdgcn_mfma_f32_16x16x32_bf16(qf[rt][0], kf[0], sc[0], 0, 0, 0);
            sc[0] = __builtin_amdgcn_mfma_f32_16x16x32_bf16(qf[rt][1], kf[1], sc[0], 0, 0, 0);
            sc[1] = __builtin_amdgcn_mfma_f32_16x16x32_bf16(qf[rt][0], kf[2], sc[1], 0, 0, 0);
            sc[1] = __builtin_amdgcn_mfma_f32_16x16x32_bf16(qf[rt][1], kf[3], sc[1], 0, 0, 0);

            if (last) {
                #pragma unroll
                for (int tt = 0; tt < 2; ++tt)
                    #pragma unroll
                    for (int r = 0; r < 4; ++r)
                        if (kv0 + tt * 16 + m > q0 + rt * 16 + g * 4 + r) sc[tt][r] = -INFINITY;
            }

            bool need = false;
            #pragma unroll
            for (int r = 0; r < 4; ++r) {
                float th = mrun[rt][r] + 8.0f;
                need = need | (sc[0][r] > th) | (sc[1][r] > th);
            }
            if (__any(need)) {
                float rmax[4];
                #pragma unroll
                for (int r = 0; r < 4; ++r) rmax[r] = fmaxf(sc[0][r], sc[1][r]);
                #pragma unroll
                for (int msk = 1; msk <= 8; msk <<= 1)
                    #pragma unroll
                    for (int r = 0; r < 4; ++r)
                        rmax[r] = fmaxf(rmax[r], __shfl_xor(rmax[r], msk));
                #pragma unroll
                for (int r = 0; r < 4; ++r) {
                    float mnew = fmaxf(mrun[rt][r], rmax[r]);
                    float alpha = __builtin_amdgcn_exp2f(mrun[rt][r] - mnew);
                    mrun[rt][r] = mnew;
                    #pragma unroll
                    for (int t = 0; t < 5; ++t) acc[rt][t][r] *= alpha;
                }
            }

            #pragma unroll
            for (int tt = 0; tt < 2; ++tt)
                #pragma unroll
                for (int r = 0; r < 4; ++r)
                    P_lds[w][rt * 16 + g * 4 + r][tt * 16 + m] =
                        f2bf(__builtin_amdgcn_exp2f(sc[tt][r] - mrun[rt][r]));
            short8 pa = *(const short8*)&P_lds[w][rt * 16 + m][g * 8];

            #pragma unroll
            for (int t = 0; t < 4; ++t)
                acc[rt][t] = __builtin_amdgcn_mfma_f32_16x16x32_bf16(pa, vcur[t], acc[rt][t], 0, 0, 0);
            acc[rt][4] = __builtin_amdgcn_mfma_f32_16x16x32_bf16(pa, onesB, acc[rt][4], 0, 0, 0);
        }
    }

    #pragma unroll
    for (int rt = 0; rt < 2; ++rt) {
        if (m == 0) {
            #pragma unroll
            for (int r = 0; r < 4; ++r) {
                pm[w][g * 4 + r] = mrun[rt][r];
                pl[w][g * 4 + r] = acc[rt][4][r];
            }
        }
        #pragma unroll
        for (int t = 0; t < 4; ++t)
            #pragma unroll
            for (int r = 0; r < 4; ++r)
                pacc[w][g * 4 + r][t * 16 + m] = f2bf(acc[rt][t][r]);
        __syncthreads();

        if (tid < 256) {
            int row = tid >> 4;
            int c4 = (tid & 15) * 4;
            float mmax = pm[0][row];
            #pragma unroll
            for (int w2 = 1; w2 < 8; ++w2) mmax = fmaxf(mmax, pm[w2][row]);
            float lt = 0.f;
            float o0 = 0.f, o1 = 0.f, o2 = 0.f, o3 = 0.f;
            #pragma unroll
            for (int w2 = 0; w2 < 8; ++w2) {
                float sc2 = __builtin_amdgcn_exp2f(pm[w2][row] - mmax);
                lt += pl[w2][row] * sc2;
                short4v pa4 = *(const short4v*)&pacc[w2][row][c4];
                o0 += bf2f((unsigned short)pa4[0]) * sc2;
                o1 += bf2f((unsigned short)pa4[1]) * sc2;
                o2 += bf2f((unsigned short)pa4[2]) * sc2;
                o3 += bf2f((unsigned short)pa4[3]) * sc2;
            }
            float invl = 1.0f / lt;
            float4 res = make_float4(o0 * invl, o1 * invl, o2 * invl, o3 * invl);
            *(float4*)&out[(size_t)(b * SEQ + q0 + rt * 16 + row) * DOUT + c4] = res;
        }
        __syncthreads();
    }
}

// ---------------------------------------------------------------------------
extern "C" void kernel_launch(void* const* d_in, const int* in_sizes, int n_in,
                              void* d_out, int out_size, void* d_ws, size_t ws_size,
                              hipStream_t stream) {
    const float* x  = (const float*)d_in[0];
    const float* wq = (const float*)d_in[1];
    const float* bq = (const float*)d_in[2];
    const float* wk = (const float*)d_in[3];
    const float* bk = (const float*)d_in[4];
    const float* wv = (const float*)d_in[5];
    const float* bv = (const float*)d_in[6];
    float* out = (float*)d_out;

    char* ws = (char*)d_ws;
    unsigned short* wF = (unsigned short*)ws;                       // 294912 B
    unsigned short* Qf = (unsigned short*)(ws + 294912);            // 2 MB
    unsigned short* Kf = (unsigned short*)(ws + 294912 + 2097152);  // 2 MB
    unsigned short* Vf = (unsigned short*)(ws + 294912 + 4194304);  // 2 MB

    wprep_kernel<<<36, 256, 0, stream>>>(wq, wk, wv, wF);
    proj_kernel<<<512, 256, 0, stream>>>(x, bq, bk, bv, wF, Qf, Kf, Vf);
    attn_kernel<<<512, 512, 0, stream>>>(Qf, Kf, Vf, out);
}

// Round 13
// 52.808 us; speedup vs baseline: 2.0748x; 1.0086x over previous
//
#include <hip/hip_runtime.h>
#include <hip/hip_bf16.h>

#define BATCH 4
#define SEQ   4096
#define DIN   768
#define DOUT  64

typedef __attribute__((ext_vector_type(4))) float f32x4;
typedef __attribute__((ext_vector_type(8))) short short8;
typedef __attribute__((ext_vector_type(4))) short short4v;

#define QSCALE 0.18033688011112043f  /* 0.125 * log2(e) */

static __device__ __forceinline__ unsigned short f2bf(float f) {
    union { float f; unsigned u; } un; un.f = f;
    unsigned r = un.u + 0x7FFF + ((un.u >> 16) & 1);
    return (unsigned short)(r >> 16);
}
static __device__ __forceinline__ float bf2f(unsigned short h) {
    union { unsigned u; float f; } un; un.u = ((unsigned)h) << 16;
    return un.f;
}

// ---------------------------------------------------------------------------
// Kernel 0 (v2, unchanged): weights -> B-fragment order.
// wF[(nc*24+kc)*512 + lane*8 + j] = w_o[kc*32 + g*8 + j][t*16 + m]
// ---------------------------------------------------------------------------
__global__ void wprep_kernel(const float* __restrict__ wq,
                             const float* __restrict__ wk,
                             const float* __restrict__ wv,
                             unsigned short* __restrict__ wF) {
    __shared__ float lds[64][65];
    int o = blockIdx.x / 12, kt = blockIdx.x % 12;
    const float* w = (o == 0) ? wq : (o == 1) ? wk : wv;
    int tid = threadIdx.x;
    int k0 = kt * 64;
    #pragma unroll
    for (int i = 0; i < 16; ++i) {
        int flat = tid + i * 256;
        int kl = flat >> 6, n = flat & 63;
        lds[kl][n] = w[(k0 + kl) * 64 + n];
    }
    __syncthreads();
    int lane = tid & 63;
    int m = lane & 15, g = lane >> 4;
    #pragma unroll
    for (int i = 0; i < 2; ++i) {
        int f = i * 4 + (tid >> 6);
        int t = f >> 1, kcl = f & 1;
        int kc = kt * 2 + kcl;
        int nc = o * 4 + t;
        short8 v;
        #pragma unroll
        for (int j = 0; j < 8; ++j)
            v[j] = (short)f2bf(lds[kcl * 32 + g * 8 + j][t * 16 + m]);
        *(short8*)&wF[(size_t)(nc * 24 + kc) * 512 + lane * 8] = v;
    }
}

// ---------------------------------------------------------------------------
// Kernel 1 (v8, unchanged): QKV projection, fragment-order I/O, 32 rows/blk.
// ---------------------------------------------------------------------------
__global__ void __launch_bounds__(256) proj_kernel(
        const float* __restrict__ x,
        const float* __restrict__ bq,
        const float* __restrict__ bk,
        const float* __restrict__ bv,
        const unsigned short* __restrict__ wF,
        unsigned short* __restrict__ Qf,
        unsigned short* __restrict__ Kf,
        unsigned short* __restrict__ Vf) {
    __shared__ __align__(16) unsigned short xs[32][776];   // 48.5 KB
    __shared__ unsigned short tr[4][16][24];               // 3 KB

    int tid = threadIdx.x;
    int w = tid >> 6;
    int lane = tid & 63;
    int m = lane & 15, g = lane >> 4;
    int r0 = blockIdx.x * 32;

    {
        const float* xbase = x + (size_t)r0 * DIN;
        #pragma unroll
        for (int i = 0; i < 24; ++i) {
            int flat4 = tid + i * 256;
            int row = flat4 / 192;
            int c4 = flat4 - row * 192;
            float4 v = *(const float4*)(xbase + (size_t)row * DIN + c4 * 4);
            short4v sv;
            sv[0] = (short)f2bf(v.x); sv[1] = (short)f2bf(v.y);
            sv[2] = (short)f2bf(v.z); sv[3] = (short)f2bf(v.w);
            *(short4v*)&xs[row][c4 * 4] = sv;
        }
    }
    __syncthreads();

    f32x4 acc[2][3];
    #pragma unroll
    for (int st = 0; st < 2; ++st)
        #pragma unroll
        for (int t = 0; t < 3; ++t) acc[st][t] = (f32x4){0.f, 0.f, 0.f, 0.f};

    for (int kc = 0; kc < 24; ++kc) {
        short8 af0 = *(const short8*)&xs[m][kc * 32 + g * 8];
        short8 af1 = *(const short8*)&xs[16 + m][kc * 32 + g * 8];
        #pragma unroll
        for (int tt = 0; tt < 3; ++tt) {
            int nc = w * 3 + tt;
            short8 bfrg = *(const short8*)(wF + (size_t)(nc * 24 + kc) * 512 + lane * 8);
            acc[0][tt] = __builtin_amdgcn_mfma_f32_16x16x32_bf16(af0, bfrg, acc[0][tt], 0, 0, 0);
            acc[1][tt] = __builtin_amdgcn_mfma_f32_16x16x32_bf16(af1, bfrg, acc[1][tt], 0, 0, 0);
        }
    }

    int b2 = r0 >> 12;
    int s = (r0 & 4095) >> 5;
    #pragma unroll
    for (int st = 0; st < 2; ++st) {
        #pragma unroll
        for (int tt = 0; tt < 3; ++tt) {
            int nc = w * 3 + tt;
            int o = nc >> 2;
            int t = nc & 3;
            const float* bias_p = (o == 0) ? bq : (o == 1) ? bk : bv;
            float bias = bias_p[t * 16 + m];
            #pragma unroll
            for (int r = 0; r < 4; ++r) {
                float val = acc[st][tt][r] + bias;
                if (o == 0) val *= QSCALE;
                tr[w][g * 4 + r][m] = f2bf(val);
            }
            if (o < 2) {
                if (g < 2) {
                    short8 v8;
                    #pragma unroll
                    for (int j = 0; j < 8; ++j) v8[j] = (short)tr[w][m][g * 8 + j];
                    unsigned short* dst = (o == 0) ? Qf : Kf;
                    int c = t >> 1;
                    *(short8*)&dst[(size_t)((blockIdx.x * 2 + st) * 2 + c) * 512
                                   + (((t & 1) * 2 + g) * 16 + m) * 8] = v8;
                }
            } else {
                if (g < 2) {
                    short8 v8;
                    #pragma unroll
                    for (int j = 0; j < 8; ++j) v8[j] = (short)tr[w][g * 8 + j][m];
                    *(short8*)&Vf[((size_t)(b2 * 128 + s) * 4 + t) * 512
                                  + ((st * 2 + g) * 16 + m) * 8] = v8;
                }
            }
        }
    }
}

// ---------------------------------------------------------------------------
// Kernel 2 (v7): identical structure to v5/round-12, ONE change:
// __launch_bounds__(512, 2) instead of (512, 4).
// The ,4 variant capped the allocator at 64 VGPR (8 waves/SIMD budget) while
// live state is ~110 -> chronic scratch spill (round-9 counters: WRITE 13MB
// vs 4.2MB out, FETCH 9.5MB vs 6MB inputs). Grid is 512 blocks = 2/CU, so
// the 4-block guarantee was never used: 128-VGPR budget is free occupancy-wise.
// ---------------------------------------------------------------------------
__global__ void __launch_bounds__(512, 2) attn_kernel(
        const unsigned short* __restrict__ Qf,
        const unsigned short* __restrict__ Kf,
        const unsigned short* __restrict__ Vf,
        float* __restrict__ out) {
    __shared__ __align__(16) unsigned short P_lds[8][32][36];
    __shared__ __align__(16) unsigned short pacc[8][16][68];
    __shared__ float pm[8][16];
    __shared__ float pl[8][16];

    int j = blockIdx.x;
    int b = (j & 7) >> 1;
    int pair = 127 - ((j >> 3) * 2 + (j & 1));
    int q0 = pair * 32;
    int nsteps = pair + 1;
    int tid = threadIdx.x;
    int w = tid >> 6;
    int lane = tid & 63;
    int m = lane & 15, g = lane >> 4;

    const unsigned short* Qbase = Qf + (size_t)(b * 256 + pair * 2) * 1024 + lane * 8;
    short8 qf[2][2];
    qf[0][0] = *(const short8*)(Qbase);
    qf[0][1] = *(const short8*)(Qbase + 512);
    qf[1][0] = *(const short8*)(Qbase + 1024);
    qf[1][1] = *(const short8*)(Qbase + 1536);

    short8 onesB = (short8){0,0,0,0,0,0,0,0};
    if (m == 0) {
        #pragma unroll
        for (int jj = 0; jj < 8; ++jj) onesB[jj] = (short)0x3F80;
    }

    f32x4 acc[2][5];
    #pragma unroll
    for (int rt = 0; rt < 2; ++rt)
        #pragma unroll
        for (int t = 0; t < 5; ++t) acc[rt][t] = (f32x4){0.f, 0.f, 0.f, 0.f};
    float mrun[2][4];
    #pragma unroll
    for (int rt = 0; rt < 2; ++rt)
        #pragma unroll
        for (int r = 0; r < 4; ++r) mrun[rt][r] = -INFINITY;

    const unsigned short* Kbase = Kf + (size_t)(b * 256) * 1024 + lane * 8;
    const unsigned short* Vbase = Vf + (size_t)(b * 128) * 2048 + lane * 8;

    for (int s = w; s < nsteps; s += 8) {
        int kv0 = s * 32;
        short8 kf[4];
        kf[0] = *(const short8*)(Kbase + (size_t)s * 2048);
        kf[1] = *(const short8*)(Kbase + (size_t)s * 2048 + 512);
        kf[2] = *(const short8*)(Kbase + (size_t)s * 2048 + 1024);
        kf[3] = *(const short8*)(Kbase + (size_t)s * 2048 + 1536);
        short8 vcur[4];
        #pragma unroll
        for (int t = 0; t < 4; ++t)
            vcur[t] = *(const short8*)(Vbase + (size_t)s * 2048 + t * 512);
        bool last = (s == nsteps - 1);

        #pragma unroll
        for (int rt = 0; rt < 2; ++rt) {
            f32x4 sc[2];
            sc[0] = (f32x4){0.f, 0.f, 0.f, 0.f};
            sc[1] = (f32x4){0.f, 0.f, 0.f, 0.f};
            sc[0] = __builtin_amdgcn_mfma_f32_16x16x32_bf16(qf[rt][0], kf[0], sc[0], 0, 0, 0);
            sc[0] = __builtin_amdgcn_mfma_f32_16x16x32_bf16(qf[rt][1], kf[1], sc[0], 0, 0, 0);
            sc[1] = __builtin_amdgcn_mfma_f32_16x16x32_bf16(qf[rt][0], kf[2], sc[1], 0, 0, 0);
            sc[1] = __builtin_amdgcn_mfma_f32_16x16x32_bf16(qf[rt][1], kf[3], sc[1], 0, 0, 0);

            if (last) {
                #pragma unroll
                for (int tt = 0; tt < 2; ++tt)
                    #pragma unroll
                    for (int r = 0; r < 4; ++r)
                        if (kv0 + tt * 16 + m > q0 + rt * 16 + g * 4 + r) sc[tt][r] = -INFINITY;
            }

            bool need = false;
            #pragma unroll
            for (int r = 0; r < 4; ++r) {
                float th = mrun[rt][r] + 8.0f;
                need = need | (sc[0][r] > th) | (sc[1][r] > th);
            }
            if (__any(need)) {
                float rmax[4];
                #pragma unroll
                for (int r = 0; r < 4; ++r) rmax[r] = fmaxf(sc[0][r], sc[1][r]);
                #pragma unroll
                for (int msk = 1; msk <= 8; msk <<= 1)
                    #pragma unroll
                    for (int r = 0; r < 4; ++r)
                        rmax[r] = fmaxf(rmax[r], __shfl_xor(rmax[r], msk));
                #pragma unroll
                for (int r = 0; r < 4; ++r) {
                    float mnew = fmaxf(mrun[rt][r], rmax[r]);
                    float alpha = __builtin_amdgcn_exp2f(mrun[rt][r] - mnew);
                    mrun[rt][r] = mnew;
                    #pragma unroll
                    for (int t = 0; t < 5; ++t) acc[rt][t][r] *= alpha;
                }
            }

            #pragma unroll
            for (int tt = 0; tt < 2; ++tt)
                #pragma unroll
                for (int r = 0; r < 4; ++r)
                    P_lds[w][rt * 16 + g * 4 + r][tt * 16 + m] =
                        f2bf(__builtin_amdgcn_exp2f(sc[tt][r] - mrun[rt][r]));
            short8 pa = *(const short8*)&P_lds[w][rt * 16 + m][g * 8];

            #pragma unroll
            for (int t = 0; t < 4; ++t)
                acc[rt][t] = __builtin_amdgcn_mfma_f32_16x16x32_bf16(pa, vcur[t], acc[rt][t], 0, 0, 0);
            acc[rt][4] = __builtin_amdgcn_mfma_f32_16x16x32_bf16(pa, onesB, acc[rt][4], 0, 0, 0);
        }
    }

    #pragma unroll
    for (int rt = 0; rt < 2; ++rt) {
        if (m == 0) {
            #pragma unroll
            for (int r = 0; r < 4; ++r) {
                pm[w][g * 4 + r] = mrun[rt][r];
                pl[w][g * 4 + r] = acc[rt][4][r];
            }
        }
        #pragma unroll
        for (int t = 0; t < 4; ++t)
            #pragma unroll
            for (int r = 0; r < 4; ++r)
                pacc[w][g * 4 + r][t * 16 + m] = f2bf(acc[rt][t][r]);
        __syncthreads();

        if (tid < 256) {
            int row = tid >> 4;
            int c4 = (tid & 15) * 4;
            float mmax = pm[0][row];
            #pragma unroll
            for (int w2 = 1; w2 < 8; ++w2) mmax = fmaxf(mmax, pm[w2][row]);
            float lt = 0.f;
            float o0 = 0.f, o1 = 0.f, o2 = 0.f, o3 = 0.f;
            #pragma unroll
            for (int w2 = 0; w2 < 8; ++w2) {
                float sc2 = __builtin_amdgcn_exp2f(pm[w2][row] - mmax);
                lt += pl[w2][row] * sc2;
                short4v pa4 = *(const short4v*)&pacc[w2][row][c4];
                o0 += bf2f((unsigned short)pa4[0]) * sc2;
                o1 += bf2f((unsigned short)pa4[1]) * sc2;
                o2 += bf2f((unsigned short)pa4[2]) * sc2;
                o3 += bf2f((unsigned short)pa4[3]) * sc2;
            }
            float invl = 1.0f / lt;
            float4 res = make_float4(o0 * invl, o1 * invl, o2 * invl, o3 * invl);
            *(float4*)&out[(size_t)(b * SEQ + q0 + rt * 16 + row) * DOUT + c4] = res;
        }
        __syncthreads();
    }
}

// ---------------------------------------------------------------------------
extern "C" void kernel_launch(void* const* d_in, const int* in_sizes, int n_in,
                              void* d_out, int out_size, void* d_ws, size_t ws_size,
                              hipStream_t stream) {
    const float* x  = (const float*)d_in[0];
    const float* wq = (const float*)d_in[1];
    const float* bq = (const float*)d_in[2];
    const float* wk = (const float*)d_in[3];
    const float* bk = (const float*)d_in[4];
    const float* wv = (const float*)d_in[5];
    const float* bv = (const float*)d_in[6];
    float* out = (float*)d_out;

    char* ws = (char*)d_ws;
    unsigned short* wF = (unsigned short*)ws;                       // 294912 B
    unsigned short* Qf = (unsigned short*)(ws + 294912);            // 2 MB
    unsigned short* Kf = (unsigned short*)(ws + 294912 + 2097152);  // 2 MB
    unsigned short* Vf = (unsigned short*)(ws + 294912 + 4194304);  // 2 MB

    wprep_kernel<<<36, 256, 0, stream>>>(wq, wk, wv, wF);
    proj_kernel<<<512, 256, 0, stream>>>(x, bq, bk, bv, wF, Qf, Kf, Vf);
    attn_kernel<<<512, 512, 0, stream>>>(Qf, Kf, Vf, out);
}